// Round 1
// baseline (2485.604 us; speedup 1.0000x reference)
//
#include <hip/hip_runtime.h>
#include <hip/hip_bf16.h>
#include <stdint.h>

#define N_TOK 65536
#define DIN   512
#define DOUT  512
#define NE    8
#define TB    64   // tokens per GEMM block

typedef __attribute__((ext_vector_type(8))) short          short8;
typedef __attribute__((ext_vector_type(8))) __bf16         bf16x8;
typedef __attribute__((ext_vector_type(8))) unsigned short ushort8;
typedef __attribute__((ext_vector_type(4))) float          f32x4;

// round-to-nearest-even fp32 -> bf16
__device__ __forceinline__ unsigned short f2bf(float f) {
  union { float f; unsigned u; } c; c.f = f;
  unsigned r = c.u + 0x7FFFu + ((c.u >> 16) & 1u);
  return (unsigned short)(r >> 16);
}

__device__ __forceinline__ f32x4 mfma16(short8 a, short8 b, f32x4 c) {
  return __builtin_amdgcn_mfma_f32_16x16x32_bf16(
      __builtin_bit_cast(bf16x8, a), __builtin_bit_cast(bf16x8, b), c, 0, 0, 0);
}

// ---------------- W fp32 -> bf16 ----------------
__global__ void __launch_bounds__(256) k_convert_w(const float* __restrict__ W,
                                                   unsigned short* __restrict__ wb) {
  int i = (blockIdx.x * 256 + threadIdx.x) * 8;  // total NE*DOUT*DIN = 2097152
  float4 a = *(const float4*)(W + i);
  float4 b = *(const float4*)(W + i + 4);
  ushort8 o;
  o[0] = f2bf(a.x); o[1] = f2bf(a.y); o[2] = f2bf(a.z); o[3] = f2bf(a.w);
  o[4] = f2bf(b.x); o[5] = f2bf(b.y); o[6] = f2bf(b.z); o[7] = f2bf(b.w);
  *(ushort8*)(wb + i) = o;
}

// ---------------- gate: fp32 scores, top-2, softmax; fused x->bf16 ----------------
// meta layout (ints): [0..15] counts, [16..32] offsets, [33..41] tileoff_k0,
//                     [42..50] tileoff_k1, [51..66] cursors
__global__ void __launch_bounds__(256) k_gate(const float* __restrict__ x,
                                              const float* __restrict__ Wg,
                                              const float* __restrict__ bg,
                                              unsigned short* __restrict__ xb,
                                              int2* __restrict__ tki,
                                              float2* __restrict__ tkw,
                                              int* __restrict__ meta) {
  __shared__ float wg_s[NE * DIN];
  __shared__ float bg_s[NE];
  int tid = threadIdx.x;
  for (int i = tid; i < NE * DIN; i += 256) wg_s[i] = Wg[i];
  if (tid < NE) bg_s[tid] = bg[tid];
  __syncthreads();

  int wid = tid >> 6, lane = tid & 63;
  int tok = blockIdx.x * 4 + wid;
  const float* xr = x + (size_t)tok * DIN + lane * 8;
  float4 v0 = *(const float4*)(xr);
  float4 v1 = *(const float4*)(xr + 4);

  ushort8 xo;
  xo[0] = f2bf(v0.x); xo[1] = f2bf(v0.y); xo[2] = f2bf(v0.z); xo[3] = f2bf(v0.w);
  xo[4] = f2bf(v1.x); xo[5] = f2bf(v1.y); xo[6] = f2bf(v1.z); xo[7] = f2bf(v1.w);
  *(ushort8*)(xb + (size_t)tok * DIN + lane * 8) = xo;

  float s[NE];
#pragma unroll
  for (int e = 0; e < NE; ++e) {
    const float* wr = wg_s + e * DIN + lane * 8;
    float4 w0 = *(const float4*)(wr);
    float4 w1 = *(const float4*)(wr + 4);
    s[e] = v0.x * w0.x + v0.y * w0.y + v0.z * w0.z + v0.w * w0.w +
           v1.x * w1.x + v1.y * w1.y + v1.z * w1.z + v1.w * w1.w;
  }
#pragma unroll
  for (int d = 1; d < 64; d <<= 1) {
#pragma unroll
    for (int e = 0; e < NE; ++e) s[e] += __shfl_xor(s[e], d, 64);
  }
  if (lane == 0) {
    float sc[NE];
#pragma unroll
    for (int e = 0; e < NE; ++e) sc[e] = s[e] + bg_s[e];
    int e0 = 0;
#pragma unroll
    for (int e = 1; e < NE; ++e) if (sc[e] > sc[e0]) e0 = e;     // strict > : lowest idx wins ties
    int e1 = (e0 == 0) ? 1 : 0;
#pragma unroll
    for (int e = 0; e < NE; ++e) if (e != e0 && sc[e] > sc[e1]) e1 = e;
    float t = expf(sc[e1] - sc[e0]);
    float inv = 1.0f / (1.0f + t);
    tki[tok] = make_int2(e0, e1);
    tkw[tok] = make_float2(inv, t * inv);
    atomicAdd(&meta[e0], 1);
    atomicAdd(&meta[8 + e1], 1);
  }
}

// ---------------- tiny serial scan ----------------
__global__ void k_scan(int* meta) {
  if (threadIdx.x == 0 && blockIdx.x == 0) {
    int off = 0;
    for (int g = 0; g < 16; ++g) { meta[16 + g] = off; off += meta[g]; }
    meta[32] = off;
    int t = 0;
    for (int e = 0; e < 8; ++e) { meta[33 + e] = t; t += (meta[e] + TB - 1) / TB; }
    meta[41] = t;
    t = 0;
    for (int e = 0; e < 8; ++e) { meta[42 + e] = t; t += (meta[8 + e] + TB - 1) / TB; }
    meta[50] = t;
  }
}

// ---------------- scatter tokens into (k,expert) buckets ----------------
__global__ void __launch_bounds__(256) k_scatter(const int2* __restrict__ tki,
                                                 int* __restrict__ list,
                                                 int* __restrict__ meta) {
  int t = blockIdx.x * 256 + threadIdx.x;
  int2 e = tki[t];
  int p0 = atomicAdd(&meta[51 + e.x], 1);
  list[meta[16 + e.x] + p0] = t;
  int p1 = atomicAdd(&meta[51 + 8 + e.y], 1);
  list[meta[16 + 8 + e.y] + p1] = t;
}

// ---------------- expert-bucketed gather GEMM ----------------
// block: 64 tokens x 512 outs, 4 waves x 128 cols, 16x16x32 bf16 MFMA
template <int KSLOT>
__global__ void __launch_bounds__(256, 2) k_moe_gemm(
    const unsigned short* __restrict__ xb, const unsigned short* __restrict__ wb,
    const float* __restrict__ bias, const float2* __restrict__ tkw,
    const int* __restrict__ list, const int* __restrict__ meta,
    float* __restrict__ out) {
  __shared__ int tok_s[TB];
  __shared__ float w_s[TB];
  const int* toff = meta + (KSLOT == 0 ? 33 : 42);
  int tile = blockIdx.x;
  if (tile >= toff[8]) return;
  int e = 0;
  while (tile >= toff[e + 1]) ++e;
  int g = KSLOT * 8 + e;
  int cnt = meta[g];
  int goff = meta[16 + g];
  int row0 = (tile - toff[e]) * TB;

  int tid = threadIdx.x;
  if (tid < TB) {
    int r = row0 + tid;
    if (r < cnt) {
      int t = list[goff + r];
      tok_s[tid] = t;
      w_s[tid] = (KSLOT == 0) ? tkw[t].x : tkw[t].y;
    } else {
      tok_s[tid] = -1;
      w_s[tid] = 0.f;
    }
  }
  __syncthreads();

  int wid = tid >> 6, lane = tid & 63;
  int obase = wid * 128;
  int lrow = lane & 15;
  int lk = (lane >> 4) * 8;

  int tokA[4];
#pragma unroll
  for (int tf = 0; tf < 4; ++tf) {
    int t = tok_s[tf * 16 + lrow];
    tokA[tf] = (t < 0) ? tok_s[0] : t;   // tok_s[0] always valid (row0 < cnt)
  }
  const unsigned short* wbase = wb + (size_t)(e * DOUT + obase + lrow) * DIN + lk;

  f32x4 acc[4][8];
#pragma unroll
  for (int tf = 0; tf < 4; ++tf)
#pragma unroll
    for (int of = 0; of < 8; ++of) acc[tf][of] = (f32x4){0.f, 0.f, 0.f, 0.f};

  for (int kk = 0; kk < DIN; kk += 64) {
    short8 a[4][2];
#pragma unroll
    for (int tf = 0; tf < 4; ++tf) {
      const unsigned short* pa = xb + (size_t)tokA[tf] * DIN + kk + lk;
      a[tf][0] = *(const short8*)(pa);
      a[tf][1] = *(const short8*)(pa + 32);
    }
#pragma unroll
    for (int of = 0; of < 8; ++of) {
      const unsigned short* pw = wbase + of * 16 * DIN + kk;
      short8 b0 = *(const short8*)(pw);
      short8 b1 = *(const short8*)(pw + 32);
#pragma unroll
      for (int tf = 0; tf < 4; ++tf) acc[tf][of] = mfma16(a[tf][0], b0, acc[tf][of]);
#pragma unroll
      for (int tf = 0; tf < 4; ++tf) acc[tf][of] = mfma16(a[tf][1], b1, acc[tf][of]);
    }
  }

  // epilogue: D layout col = lane&15, row = (lane>>4)*4 + j
#pragma unroll
  for (int tf = 0; tf < 4; ++tf) {
    int rb = tf * 16 + (lane >> 4) * 4;
    int tj[4]; float wj[4];
#pragma unroll
    for (int j = 0; j < 4; ++j) { tj[j] = tok_s[rb + j]; wj[j] = w_s[rb + j]; }
#pragma unroll
    for (int of = 0; of < 8; ++of) {
      int col = obase + of * 16 + lrow;
      float bv = bias[e * DOUT + col];
#pragma unroll
      for (int j = 0; j < 4; ++j) {
        if (tj[j] >= 0) {
          float v = wj[j] * (acc[tf][of][j] + bv);
          float* po = out + (size_t)tj[j] * DOUT + col;
          if (KSLOT == 0) *po = v; else *po += v;
        }
      }
    }
  }
}

extern "C" void kernel_launch(void* const* d_in, const int* in_sizes, int n_in,
                              void* d_out, int out_size, void* d_ws, size_t ws_size,
                              hipStream_t stream) {
  const float* x  = (const float*)d_in[0];
  const float* W  = (const float*)d_in[1];
  const float* b  = (const float*)d_in[2];
  const float* Wg = (const float*)d_in[3];
  const float* bg = (const float*)d_in[4];
  float* out = (float*)d_out;

  char* ws = (char*)d_ws;
  unsigned short* xb  = (unsigned short*)(ws);                    // 64 MB
  unsigned short* wb  = (unsigned short*)(ws + 67108864);         // 4 MB
  int2*   tki  = (int2*)(ws + 71303168);                          // 512 KB
  float2* tkw  = (float2*)(ws + 71827456);                        // 512 KB
  int*    list = (int*)(ws + 72351744);                           // 512 KB
  int*    meta = (int*)(ws + 72876032);                           // 68 ints

  hipMemsetAsync(meta, 0, 68 * sizeof(int), stream);
  k_convert_w<<<NE * DOUT * DIN / (256 * 8), 256, 0, stream>>>(W, wb);
  k_gate<<<N_TOK / 4, 256, 0, stream>>>(x, Wg, bg, xb, tki, tkw, meta);
  k_scan<<<1, 64, 0, stream>>>(meta);
  k_scatter<<<N_TOK / 256, 256, 0, stream>>>(tki, list, meta);
  int gtiles = N_TOK / TB + NE;  // worst-case tile count per k-slot
  k_moe_gemm<0><<<gtiles, 256, 0, stream>>>(xb, wb, b, tkw, list, meta, out);
  k_moe_gemm<1><<<gtiles, 256, 0, stream>>>(xb, wb, b, tkw, list, meta, out);
}

// Round 2
// 628.020 us; speedup vs baseline: 3.9578x; 3.9578x over previous
//
#include <hip/hip_runtime.h>
#include <hip/hip_bf16.h>
#include <stdint.h>

#define N_TOK 65536
#define DIN   512
#define DOUT  512
#define NE    8
#define TB    64   // tokens per GEMM block

// meta layout (ints), atomically-updated counters padded to 64B lines:
#define M_CNT(g)  ((g) * 16)        // 16 counters at 0,16,...,240
#define M_OFF     256               // bucket offsets [256..272]
#define M_T0      280               // k0 tile offsets [280..288]
#define M_T1      290               // k1 tile offsets [290..298]
#define M_CUR(g)  (320 + (g) * 16)  // 16 scatter cursors, padded
#define M_TOTAL   576

typedef __attribute__((ext_vector_type(8))) short          short8;
typedef __attribute__((ext_vector_type(8))) __bf16         bf16x8;
typedef __attribute__((ext_vector_type(8))) unsigned short ushort8;
typedef __attribute__((ext_vector_type(4))) float          f32x4;

// round-to-nearest-even fp32 -> bf16
__device__ __forceinline__ unsigned short f2bf(float f) {
  union { float f; unsigned u; } c; c.f = f;
  unsigned r = c.u + 0x7FFFu + ((c.u >> 16) & 1u);
  return (unsigned short)(r >> 16);
}

__device__ __forceinline__ f32x4 mfma16(short8 a, short8 b, f32x4 c) {
  return __builtin_amdgcn_mfma_f32_16x16x32_bf16(
      __builtin_bit_cast(bf16x8, a), __builtin_bit_cast(bf16x8, b), c, 0, 0, 0);
}

// ---------------- W fp32 -> bf16 ----------------
__global__ void __launch_bounds__(256) k_convert_w(const float* __restrict__ W,
                                                   unsigned short* __restrict__ wb) {
  int i = (blockIdx.x * 256 + threadIdx.x) * 8;
  float4 a = *(const float4*)(W + i);
  float4 b = *(const float4*)(W + i + 4);
  ushort8 o;
  o[0] = f2bf(a.x); o[1] = f2bf(a.y); o[2] = f2bf(a.z); o[3] = f2bf(a.w);
  o[4] = f2bf(b.x); o[5] = f2bf(b.y); o[6] = f2bf(b.z); o[7] = f2bf(b.w);
  *(ushort8*)(wb + i) = o;
}

// ---------------- gate: fp32 scores, top-2, softmax; fused x->bf16 ----------------
// Wg in registers (no LDS bank conflicts); counts via LDS histogram, one padded
// global atomic per (k,expert) per block.
__global__ void __launch_bounds__(256) k_gate(const float* __restrict__ x,
                                              const float* __restrict__ Wg,
                                              const float* __restrict__ bg,
                                              unsigned short* __restrict__ xb,
                                              int2* __restrict__ tki,
                                              float2* __restrict__ tkw,
                                              int* __restrict__ meta) {
  __shared__ int hist[16];
  int tid = threadIdx.x;
  if (tid < 16) hist[tid] = 0;
  int wid = tid >> 6, lane = tid & 63;

  float4 wg0[NE], wg1[NE];
#pragma unroll
  for (int e = 0; e < NE; ++e) {
    wg0[e] = *(const float4*)(Wg + e * DIN + lane * 8);
    wg1[e] = *(const float4*)(Wg + e * DIN + lane * 8 + 4);
  }
  float bgr[NE];
#pragma unroll
  for (int e = 0; e < NE; ++e) bgr[e] = bg[e];
  __syncthreads();

  for (int tok = blockIdx.x * 4 + wid; tok < N_TOK; tok += gridDim.x * 4) {
    const float* xr = x + (size_t)tok * DIN + lane * 8;
    float4 v0 = *(const float4*)(xr);
    float4 v1 = *(const float4*)(xr + 4);

    ushort8 xo;
    xo[0] = f2bf(v0.x); xo[1] = f2bf(v0.y); xo[2] = f2bf(v0.z); xo[3] = f2bf(v0.w);
    xo[4] = f2bf(v1.x); xo[5] = f2bf(v1.y); xo[6] = f2bf(v1.z); xo[7] = f2bf(v1.w);
    *(ushort8*)(xb + (size_t)tok * DIN + lane * 8) = xo;

    float s[NE];
#pragma unroll
    for (int e = 0; e < NE; ++e) {
      s[e] = v0.x * wg0[e].x + v0.y * wg0[e].y + v0.z * wg0[e].z + v0.w * wg0[e].w +
             v1.x * wg1[e].x + v1.y * wg1[e].y + v1.z * wg1[e].z + v1.w * wg1[e].w;
    }
#pragma unroll
    for (int d = 1; d < 64; d <<= 1) {
#pragma unroll
      for (int e = 0; e < NE; ++e) s[e] += __shfl_xor(s[e], d, 64);
    }
    if (lane == 0) {
      float sc[NE];
#pragma unroll
      for (int e = 0; e < NE; ++e) sc[e] = s[e] + bgr[e];
      int e0 = 0;
#pragma unroll
      for (int e = 1; e < NE; ++e) if (sc[e] > sc[e0]) e0 = e;   // strict >: lowest idx wins ties
      int e1 = (e0 == 0) ? 1 : 0;
#pragma unroll
      for (int e = 0; e < NE; ++e) if (e != e0 && sc[e] > sc[e1]) e1 = e;
      float t = expf(sc[e1] - sc[e0]);
      float inv = 1.0f / (1.0f + t);
      tki[tok] = make_int2(e0, e1);
      tkw[tok] = make_float2(inv, t * inv);
      atomicAdd(&hist[e0], 1);
      atomicAdd(&hist[8 + e1], 1);
    }
  }
  __syncthreads();
  if (tid < 16) atomicAdd(&meta[M_CNT(tid)], hist[tid]);
}

// ---------------- tiny serial scan ----------------
__global__ void k_scan(int* meta) {
  if (threadIdx.x == 0 && blockIdx.x == 0) {
    int off = 0;
    for (int g = 0; g < 16; ++g) { meta[M_OFF + g] = off; off += meta[M_CNT(g)]; }
    meta[M_OFF + 16] = off;
    int t = 0;
    for (int e = 0; e < 8; ++e) { meta[M_T0 + e] = t; t += (meta[M_CNT(e)] + TB - 1) / TB; }
    meta[M_T0 + 8] = t;
    t = 0;
    for (int e = 0; e < 8; ++e) { meta[M_T1 + e] = t; t += (meta[M_CNT(8 + e)] + TB - 1) / TB; }
    meta[M_T1 + 8] = t;
  }
}

// ---------------- scatter: block-level reservation ----------------
__global__ void __launch_bounds__(256) k_scatter(const int2* __restrict__ tki,
                                                 int* __restrict__ list,
                                                 int* __restrict__ meta) {
  __shared__ int lcnt[16];
  __shared__ int lbase[16];
  int tid = threadIdx.x;
  if (tid < 16) lcnt[tid] = 0;
  __syncthreads();
  int t = blockIdx.x * 256 + tid;
  int2 e = tki[t];
  int p0 = atomicAdd(&lcnt[e.x], 1);
  int p1 = atomicAdd(&lcnt[8 + e.y], 1);
  __syncthreads();
  if (tid < 16) lbase[tid] = atomicAdd(&meta[M_CUR(tid)], lcnt[tid]);
  __syncthreads();
  list[meta[M_OFF + e.x] + lbase[e.x] + p0] = t;
  list[meta[M_OFF + 8 + e.y] + lbase[8 + e.y] + p1] = t;
}

// ---------------- expert-bucketed gather GEMM ----------------
// block: 64 tokens x 512 outs, 4 waves x 128 cols, 16x16x32 bf16 MFMA
template <int KSLOT>
__global__ void __launch_bounds__(256, 2) k_moe_gemm(
    const unsigned short* __restrict__ xb, const unsigned short* __restrict__ wb,
    const float* __restrict__ bias, const float2* __restrict__ tkw,
    const int* __restrict__ list, const int* __restrict__ meta,
    float* __restrict__ out) {
  __shared__ int tok_s[TB];
  __shared__ float w_s[TB];
  const int* toff = meta + (KSLOT == 0 ? M_T0 : M_T1);
  int tile = blockIdx.x;
  if (tile >= toff[8]) return;
  int e = 0;
  while (tile >= toff[e + 1]) ++e;
  int g = KSLOT * 8 + e;
  int cnt = meta[M_CNT(g)];
  int goff = meta[M_OFF + g];
  int row0 = (tile - toff[e]) * TB;

  int tid = threadIdx.x;
  if (tid < TB) {
    int r = row0 + tid;
    if (r < cnt) {
      int t = list[goff + r];
      tok_s[tid] = t;
      w_s[tid] = (KSLOT == 0) ? tkw[t].x : tkw[t].y;
    } else {
      tok_s[tid] = -1;
      w_s[tid] = 0.f;
    }
  }
  __syncthreads();

  int wid = tid >> 6, lane = tid & 63;
  int obase = wid * 128;
  int lrow = lane & 15;
  int lk = (lane >> 4) * 8;

  int tokA[4];
#pragma unroll
  for (int tf = 0; tf < 4; ++tf) {
    int t = tok_s[tf * 16 + lrow];
    tokA[tf] = (t < 0) ? tok_s[0] : t;   // tok_s[0] always valid (row0 < cnt)
  }
  const unsigned short* wbase = wb + (size_t)(e * DOUT + obase + lrow) * DIN + lk;

  f32x4 acc[4][8];
#pragma unroll
  for (int tf = 0; tf < 4; ++tf)
#pragma unroll
    for (int of = 0; of < 8; ++of) acc[tf][of] = (f32x4){0.f, 0.f, 0.f, 0.f};

  for (int kk = 0; kk < DIN; kk += 64) {
    short8 a[4][2];
#pragma unroll
    for (int tf = 0; tf < 4; ++tf) {
      const unsigned short* pa = xb + (size_t)tokA[tf] * DIN + kk + lk;
      a[tf][0] = *(const short8*)(pa);
      a[tf][1] = *(const short8*)(pa + 32);
    }
#pragma unroll
    for (int of = 0; of < 8; ++of) {
      const unsigned short* pw = wbase + of * 16 * DIN + kk;
      short8 b0 = *(const short8*)(pw);
      short8 b1 = *(const short8*)(pw + 32);
#pragma unroll
      for (int tf = 0; tf < 4; ++tf) acc[tf][of] = mfma16(a[tf][0], b0, acc[tf][of]);
#pragma unroll
      for (int tf = 0; tf < 4; ++tf) acc[tf][of] = mfma16(a[tf][1], b1, acc[tf][of]);
    }
  }

  // epilogue: D layout col = lane&15, row = (lane>>4)*4 + j
#pragma unroll
  for (int tf = 0; tf < 4; ++tf) {
    int rb = tf * 16 + (lane >> 4) * 4;
    int tj[4]; float wj[4];
#pragma unroll
    for (int j = 0; j < 4; ++j) { tj[j] = tok_s[rb + j]; wj[j] = w_s[rb + j]; }
#pragma unroll
    for (int of = 0; of < 8; ++of) {
      int col = obase + of * 16 + lrow;
      float bv = bias[e * DOUT + col];
#pragma unroll
      for (int j = 0; j < 4; ++j) {
        if (tj[j] >= 0) {
          float v = wj[j] * (acc[tf][of][j] + bv);
          float* po = out + (size_t)tj[j] * DOUT + col;
          if (KSLOT == 0) *po = v; else *po += v;
        }
      }
    }
  }
}

extern "C" void kernel_launch(void* const* d_in, const int* in_sizes, int n_in,
                              void* d_out, int out_size, void* d_ws, size_t ws_size,
                              hipStream_t stream) {
  const float* x  = (const float*)d_in[0];
  const float* W  = (const float*)d_in[1];
  const float* b  = (const float*)d_in[2];
  const float* Wg = (const float*)d_in[3];
  const float* bg = (const float*)d_in[4];
  float* out = (float*)d_out;

  char* ws = (char*)d_ws;
  unsigned short* xb  = (unsigned short*)(ws);                    // 64 MB
  unsigned short* wb  = (unsigned short*)(ws + 67108864);         // 4 MB
  int2*   tki  = (int2*)(ws + 71303168);                          // 512 KB
  float2* tkw  = (float2*)(ws + 71827456);                        // 512 KB
  int*    list = (int*)(ws + 72351744);                           // 512 KB
  int*    meta = (int*)(ws + 72876032);                           // M_TOTAL ints

  hipMemsetAsync(meta, 0, M_TOTAL * sizeof(int), stream);
  k_convert_w<<<NE * DOUT * DIN / (256 * 8), 256, 0, stream>>>(W, wb);
  k_gate<<<2048, 256, 0, stream>>>(x, Wg, bg, xb, tki, tkw, meta);
  k_scan<<<1, 64, 0, stream>>>(meta);
  k_scatter<<<N_TOK / 256, 256, 0, stream>>>(tki, list, meta);
  int gtiles = N_TOK / TB + NE;  // worst-case tile count per k-slot
  k_moe_gemm<0><<<gtiles, 256, 0, stream>>>(xb, wb, b, tkw, list, meta, out);
  k_moe_gemm<1><<<gtiles, 256, 0, stream>>>(xb, wb, b, tkw, list, meta, out);
}

// Round 3
// 511.809 us; speedup vs baseline: 4.8565x; 1.2271x over previous
//
#include <hip/hip_runtime.h>
#include <hip/hip_bf16.h>
#include <stdint.h>

#define N_TOK 65536
#define DIN   512
#define DOUT  512
#define NE    8
#define TB    128        // tokens per GEMM M-tile
#define NKT   (DIN / 64) // 8 K-steps of 64

// meta layout (ints), atomically-updated counters padded to 64B lines:
#define M_CNT(g)  ((g) * 16)        // 16 counters at 0,16,...,240
#define M_OFF     256               // bucket offsets [256..272]
#define M_T0      280               // k0 M-tile offsets [280..288]
#define M_T1      290               // k1 M-tile offsets [290..298]
#define M_CUR(g)  (320 + (g) * 16)  // 16 scatter cursors, padded
#define M_TOTAL   576

typedef __attribute__((ext_vector_type(8))) short          short8;
typedef __attribute__((ext_vector_type(8))) __bf16         bf16x8;
typedef __attribute__((ext_vector_type(8))) unsigned short ushort8;
typedef __attribute__((ext_vector_type(4))) float          f32x4;

// round-to-nearest-even fp32 -> bf16
__device__ __forceinline__ unsigned short f2bf(float f) {
  union { float f; unsigned u; } c; c.f = f;
  unsigned r = c.u + 0x7FFFu + ((c.u >> 16) & 1u);
  return (unsigned short)(r >> 16);
}

__device__ __forceinline__ f32x4 mfma16(short8 a, short8 b, f32x4 c) {
  return __builtin_amdgcn_mfma_f32_16x16x32_bf16(
      __builtin_bit_cast(bf16x8, a), __builtin_bit_cast(bf16x8, b), c, 0, 0, 0);
}

// async global->LDS, 16B per lane; LDS dest = wave-uniform base + lane*16 (linear),
// global src is PER-LANE (gather legal).
__device__ __forceinline__ void gl16(const void* g, void* l) {
  __builtin_amdgcn_global_load_lds(
      (const __attribute__((address_space(1))) unsigned int*)g,
      (__attribute__((address_space(3))) unsigned int*)l, 16, 0, 0);
}

// ---------------- W fp32 -> bf16 ----------------
__global__ void __launch_bounds__(256) k_convert_w(const float* __restrict__ W,
                                                   unsigned short* __restrict__ wb) {
  int i = (blockIdx.x * 256 + threadIdx.x) * 8;
  float4 a = *(const float4*)(W + i);
  float4 b = *(const float4*)(W + i + 4);
  ushort8 o;
  o[0] = f2bf(a.x); o[1] = f2bf(a.y); o[2] = f2bf(a.z); o[3] = f2bf(a.w);
  o[4] = f2bf(b.x); o[5] = f2bf(b.y); o[6] = f2bf(b.z); o[7] = f2bf(b.w);
  *(ushort8*)(wb + i) = o;
}

// ---------------- gate: fp32 scores, top-2, softmax; fused x->bf16 ----------------
__global__ void __launch_bounds__(256) k_gate(const float* __restrict__ x,
                                              const float* __restrict__ Wg,
                                              const float* __restrict__ bg,
                                              unsigned short* __restrict__ xb,
                                              int2* __restrict__ tki,
                                              float2* __restrict__ tkw,
                                              int* __restrict__ meta) {
  __shared__ int hist[16];
  int tid = threadIdx.x;
  if (tid < 16) hist[tid] = 0;
  int wid = tid >> 6, lane = tid & 63;

  float4 wg0[NE], wg1[NE];
#pragma unroll
  for (int e = 0; e < NE; ++e) {
    wg0[e] = *(const float4*)(Wg + e * DIN + lane * 8);
    wg1[e] = *(const float4*)(Wg + e * DIN + lane * 8 + 4);
  }
  float bgr[NE];
#pragma unroll
  for (int e = 0; e < NE; ++e) bgr[e] = bg[e];
  __syncthreads();

  for (int tok = blockIdx.x * 4 + wid; tok < N_TOK; tok += gridDim.x * 4) {
    const float* xr = x + (size_t)tok * DIN + lane * 8;
    float4 v0 = *(const float4*)(xr);
    float4 v1 = *(const float4*)(xr + 4);

    ushort8 xo;
    xo[0] = f2bf(v0.x); xo[1] = f2bf(v0.y); xo[2] = f2bf(v0.z); xo[3] = f2bf(v0.w);
    xo[4] = f2bf(v1.x); xo[5] = f2bf(v1.y); xo[6] = f2bf(v1.z); xo[7] = f2bf(v1.w);
    *(ushort8*)(xb + (size_t)tok * DIN + lane * 8) = xo;

    float s[NE];
#pragma unroll
    for (int e = 0; e < NE; ++e) {
      s[e] = v0.x * wg0[e].x + v0.y * wg0[e].y + v0.z * wg0[e].z + v0.w * wg0[e].w +
             v1.x * wg1[e].x + v1.y * wg1[e].y + v1.z * wg1[e].z + v1.w * wg1[e].w;
    }
#pragma unroll
    for (int d = 1; d < 64; d <<= 1) {
#pragma unroll
      for (int e = 0; e < NE; ++e) s[e] += __shfl_xor(s[e], d, 64);
    }
    if (lane == 0) {
      float sc[NE];
#pragma unroll
      for (int e = 0; e < NE; ++e) sc[e] = s[e] + bgr[e];
      int e0 = 0;
#pragma unroll
      for (int e = 1; e < NE; ++e) if (sc[e] > sc[e0]) e0 = e;   // strict >: lowest idx wins ties
      int e1 = (e0 == 0) ? 1 : 0;
#pragma unroll
      for (int e = 0; e < NE; ++e) if (e != e0 && sc[e] > sc[e1]) e1 = e;
      float t = expf(sc[e1] - sc[e0]);
      float inv = 1.0f / (1.0f + t);
      tki[tok] = make_int2(e0, e1);
      tkw[tok] = make_float2(inv, t * inv);
      atomicAdd(&hist[e0], 1);
      atomicAdd(&hist[8 + e1], 1);
    }
  }
  __syncthreads();
  if (tid < 16) atomicAdd(&meta[M_CNT(tid)], hist[tid]);
}

// ---------------- tiny serial scan ----------------
__global__ void k_scan(int* meta) {
  if (threadIdx.x == 0 && blockIdx.x == 0) {
    int off = 0;
    for (int g = 0; g < 16; ++g) { meta[M_OFF + g] = off; off += meta[M_CNT(g)]; }
    meta[M_OFF + 16] = off;
    int t = 0;
    for (int e = 0; e < 8; ++e) { meta[M_T0 + e] = t; t += (meta[M_CNT(e)] + TB - 1) / TB; }
    meta[M_T0 + 8] = t;
    t = 0;
    for (int e = 0; e < 8; ++e) { meta[M_T1 + e] = t; t += (meta[M_CNT(8 + e)] + TB - 1) / TB; }
    meta[M_T1 + 8] = t;
  }
}

// ---------------- scatter: block-level reservation ----------------
__global__ void __launch_bounds__(256) k_scatter(const int2* __restrict__ tki,
                                                 int* __restrict__ list,
                                                 int* __restrict__ meta) {
  __shared__ int lcnt[16];
  __shared__ int lbase[16];
  int tid = threadIdx.x;
  if (tid < 16) lcnt[tid] = 0;
  __syncthreads();
  int t = blockIdx.x * 256 + tid;
  int2 e = tki[t];
  int p0 = atomicAdd(&lcnt[e.x], 1);
  int p1 = atomicAdd(&lcnt[8 + e.y], 1);
  __syncthreads();
  if (tid < 16) lbase[tid] = atomicAdd(&meta[M_CUR(tid)], lcnt[tid]);
  __syncthreads();
  list[meta[M_OFF + e.x] + lbase[e.x] + p0] = t;
  list[meta[M_OFF + 8 + e.y] + lbase[8 + e.y] + p1] = t;
}

// ---------------- expert-bucketed gather GEMM, m97 structure ----------------
// 128 tokens x 128 outs per block, BK=64, 4 waves (2x2), 4x4 frags of 16x16x32,
// double-buffered LDS via global_load_lds(16B), 2-phase barrier loop.
template <int KSLOT>
__global__ void __launch_bounds__(256) k_moe_gemm(
    const unsigned short* __restrict__ xb, const unsigned short* __restrict__ wb,
    const float* __restrict__ bias, const float2* __restrict__ tkw,
    const int* __restrict__ list, const int* __restrict__ meta,
    float* __restrict__ out) {
  __shared__ __align__(16) unsigned short As[2][TB * 64];
  __shared__ __align__(16) unsigned short Bs[2][128 * 64];
  __shared__ int tok_s[TB];
  __shared__ float w_s[TB];

  const int* toff = meta + (KSLOT == 0 ? M_T0 : M_T1);
  int mt = blockIdx.x >> 2, nb = blockIdx.x & 3;
  if (mt >= toff[8]) return;
  int e = 0;
  while (mt >= toff[e + 1]) ++e;
  int g = KSLOT * 8 + e;
  int cnt = meta[M_CNT(g)];
  int goff = meta[M_OFF + g];
  int row0 = (mt - toff[e]) * TB;
  int bn0 = nb * 128;

  int tid = threadIdx.x;
  if (tid < TB) {
    int r = row0 + tid;
    int t = (r < cnt) ? list[goff + r] : -1;
    tok_s[tid] = t;
    w_s[tid] = (t >= 0) ? ((KSLOT == 0) ? tkw[t].x : tkw[t].y) : 0.f;
  }
  __syncthreads();

  int wid = tid >> 6, lane = tid & 63;
  // --- staging addressing: wave w fills rows [w*32, w*32+32), 4 instrs each for A,B
  int sseg = lane & 7;                 // 16B segment within a 128B row
  int srow = wid * 32 + (lane >> 3);   // + j*8
  int tokS[4];
#pragma unroll
  for (int j = 0; j < 4; ++j) {
    int t = tok_s[srow + j * 8];
    tokS[j] = (t < 0) ? tok_s[0] : t;  // tok_s[0] always valid when tile exists
  }
  const unsigned short* aSrc[4];
#pragma unroll
  for (int j = 0; j < 4; ++j) aSrc[j] = xb + (size_t)tokS[j] * DIN + sseg * 8;
  const unsigned short* bSrc =
      wb + (size_t)(e * DOUT + bn0 + srow) * DIN + sseg * 8;

  int wr = wid >> 1, wc = wid & 1;
  int lrow = lane & 15, hi = lane >> 4;

  f32x4 acc[4][4];
#pragma unroll
  for (int m = 0; m < 4; ++m)
#pragma unroll
    for (int n = 0; n < 4; ++n) acc[m][n] = (f32x4){0.f, 0.f, 0.f, 0.f};

  // prologue
#pragma unroll
  for (int j = 0; j < 4; ++j) {
    gl16(aSrc[j], &As[0][(wid * 32 + j * 8) * 64]);
    gl16(bSrc + (size_t)j * 8 * DIN, &Bs[0][(wid * 32 + j * 8) * 64]);
  }
  __syncthreads();

  int cur = 0;
  for (int kt = 0; kt < NKT; ++kt) {
    if (kt + 1 < NKT) {
      int ko = (kt + 1) * 64;
#pragma unroll
      for (int j = 0; j < 4; ++j) {
        gl16(aSrc[j] + ko, &As[cur ^ 1][(wid * 32 + j * 8) * 64]);
        gl16(bSrc + (size_t)j * 8 * DIN + ko, &Bs[cur ^ 1][(wid * 32 + j * 8) * 64]);
      }
    }
#pragma unroll
    for (int kk = 0; kk < 2; ++kk) {
      short8 af[4], bf[4];
#pragma unroll
      for (int m = 0; m < 4; ++m)
        af[m] = *(const short8*)&As[cur][(wr * 64 + m * 16 + lrow) * 64 + kk * 32 + hi * 8];
#pragma unroll
      for (int n = 0; n < 4; ++n)
        bf[n] = *(const short8*)&Bs[cur][(wc * 64 + n * 16 + lrow) * 64 + kk * 32 + hi * 8];
#pragma unroll
      for (int m = 0; m < 4; ++m)
#pragma unroll
        for (int n = 0; n < 4; ++n) acc[m][n] = mfma16(af[m], bf[n], acc[m][n]);
    }
    __syncthreads();
    cur ^= 1;
  }

  // epilogue: token = wr*64+m*16+hi*4+j, col = bn0+wc*64+n*16+lrow
#pragma unroll
  for (int m = 0; m < 4; ++m) {
    int rb = wr * 64 + m * 16 + hi * 4;
    int tj[4]; float wj[4];
#pragma unroll
    for (int j = 0; j < 4; ++j) { tj[j] = tok_s[rb + j]; wj[j] = w_s[rb + j]; }
#pragma unroll
    for (int n = 0; n < 4; ++n) {
      int col = bn0 + wc * 64 + n * 16 + lrow;
      float bv = bias[e * DOUT + col];
#pragma unroll
      for (int j = 0; j < 4; ++j) {
        if (tj[j] >= 0) {
          float v = wj[j] * (acc[m][n][j] + bv);
          float* po = out + (size_t)tj[j] * DOUT + col;
          if (KSLOT == 0) *po = v; else *po += v;
        }
      }
    }
  }
}

extern "C" void kernel_launch(void* const* d_in, const int* in_sizes, int n_in,
                              void* d_out, int out_size, void* d_ws, size_t ws_size,
                              hipStream_t stream) {
  const float* x  = (const float*)d_in[0];
  const float* W  = (const float*)d_in[1];
  const float* b  = (const float*)d_in[2];
  const float* Wg = (const float*)d_in[3];
  const float* bg = (const float*)d_in[4];
  float* out = (float*)d_out;

  char* ws = (char*)d_ws;
  unsigned short* xb  = (unsigned short*)(ws);                    // 64 MB
  unsigned short* wb  = (unsigned short*)(ws + 67108864);         // 4 MB
  int2*   tki  = (int2*)(ws + 71303168);                          // 512 KB
  float2* tkw  = (float2*)(ws + 71827456);                        // 512 KB
  int*    list = (int*)(ws + 72351744);                           // 512 KB
  int*    meta = (int*)(ws + 72876032);                           // M_TOTAL ints

  hipMemsetAsync(meta, 0, M_TOTAL * sizeof(int), stream);
  k_convert_w<<<NE * DOUT * DIN / (256 * 8), 256, 0, stream>>>(W, wb);
  k_gate<<<2048, 256, 0, stream>>>(x, Wg, bg, xb, tki, tkw, meta);
  k_scan<<<1, 64, 0, stream>>>(meta);
  k_scatter<<<N_TOK / 256, 256, 0, stream>>>(tki, list, meta);
  int gtiles = (N_TOK / TB + NE) * 4;  // worst-case (M-tiles x 4 N-tiles) per k-slot
  k_moe_gemm<0><<<gtiles, 256, 0, stream>>>(xb, wb, b, tkw, list, meta, out);
  k_moe_gemm<1><<<gtiles, 256, 0, stream>>>(xb, wb, b, tkw, list, meta, out);
}

// Round 4
// 431.148 us; speedup vs baseline: 5.7651x; 1.1871x over previous
//
#include <hip/hip_runtime.h>
#include <hip/hip_bf16.h>
#include <stdint.h>

#define N_TOK 65536
#define DIN   512
#define DOUT  512
#define NE    8
#define TB    128            // tokens per GEMM M-tile
#define NMT_MAX 576          // worst-case M-tiles: 512 full + <=56 partial (+pad)
#define GRID_GEMM (NMT_MAX * 4)   // 2304, divisible by 8
#define PER_XCD   (GRID_GEMM / 8) // 288

// meta layout (ints); atomically-updated counters padded to 64B lines:
#define M_CNT(g)  ((g) * 16)        // 64 pair-bucket counters [0,1024)
#define M_OFF     1024              // bucket offsets [1024..1088]
#define M_T0      1090              // M-tile offsets [1090..1154]
#define M_NW      1156              // total work items (tiles*4)
#define M_CUR(g)  (1216 + (g) * 16) // 64 scatter cursors [1216,2240)
#define M_MAP     2240              // tile -> bucket map [2240,2240+NMT_MAX)
#define M_TOTAL   (2240 + NMT_MAX)

typedef __attribute__((ext_vector_type(8))) short          short8;
typedef __attribute__((ext_vector_type(8))) __bf16         bf16x8;
typedef __attribute__((ext_vector_type(8))) unsigned short ushort8;
typedef __attribute__((ext_vector_type(4))) float          f32x4;

// round-to-nearest-even fp32 -> bf16
__device__ __forceinline__ unsigned short f2bf(float f) {
  union { float f; unsigned u; } c; c.f = f;
  unsigned r = c.u + 0x7FFFu + ((c.u >> 16) & 1u);
  return (unsigned short)(r >> 16);
}

__device__ __forceinline__ f32x4 mfma16(short8 a, short8 b, f32x4 c) {
  return __builtin_amdgcn_mfma_f32_16x16x32_bf16(
      __builtin_bit_cast(bf16x8, a), __builtin_bit_cast(bf16x8, b), c, 0, 0, 0);
}

// async global->LDS, 16B/lane; LDS dest = wave-uniform base + lane*16 (linear),
// global src is per-lane (gather legal).
__device__ __forceinline__ void gl16(const void* g, void* l) {
  __builtin_amdgcn_global_load_lds(
      (const __attribute__((address_space(1))) unsigned int*)g,
      (__attribute__((address_space(3))) unsigned int*)l, 16, 0, 0);
}

// ---------------- W fp32 -> bf16 ----------------
__global__ void __launch_bounds__(256) k_convert_w(const float* __restrict__ W,
                                                   unsigned short* __restrict__ wb) {
  int i = (blockIdx.x * 256 + threadIdx.x) * 8;
  float4 a = *(const float4*)(W + i);
  float4 b = *(const float4*)(W + i + 4);
  ushort8 o;
  o[0] = f2bf(a.x); o[1] = f2bf(a.y); o[2] = f2bf(a.z); o[3] = f2bf(a.w);
  o[4] = f2bf(b.x); o[5] = f2bf(b.y); o[6] = f2bf(b.z); o[7] = f2bf(b.w);
  *(ushort8*)(wb + i) = o;
}

// ---------------- gate: fp32 scores, top-2, softmax; fused x->bf16 ----------------
// tkw = (w0, t) with w0 = 1/(1+t), t = exp(sc1 - sc0) <= 1 (so w1 = w0*t).
__global__ void __launch_bounds__(256, 4) k_gate(const float* __restrict__ x,
                                                 const float* __restrict__ Wg,
                                                 const float* __restrict__ bg,
                                                 unsigned short* __restrict__ xb,
                                                 int2* __restrict__ tki,
                                                 float2* __restrict__ tkw,
                                                 int* __restrict__ meta) {
  __shared__ int hist[64];
  int tid = threadIdx.x;
  if (tid < 64) hist[tid] = 0;
  int wid = tid >> 6, lane = tid & 63;

  float4 wg0[NE], wg1[NE];
#pragma unroll
  for (int e = 0; e < NE; ++e) {
    wg0[e] = *(const float4*)(Wg + e * DIN + lane * 8);
    wg1[e] = *(const float4*)(Wg + e * DIN + lane * 8 + 4);
  }
  float bgr[NE];
#pragma unroll
  for (int e = 0; e < NE; ++e) bgr[e] = bg[e];
  __syncthreads();

  for (int tok = blockIdx.x * 4 + wid; tok < N_TOK; tok += gridDim.x * 4) {
    const float* xr = x + (size_t)tok * DIN + lane * 8;
    float4 v0 = *(const float4*)(xr);
    float4 v1 = *(const float4*)(xr + 4);

    ushort8 xo;
    xo[0] = f2bf(v0.x); xo[1] = f2bf(v0.y); xo[2] = f2bf(v0.z); xo[3] = f2bf(v0.w);
    xo[4] = f2bf(v1.x); xo[5] = f2bf(v1.y); xo[6] = f2bf(v1.z); xo[7] = f2bf(v1.w);
    *(ushort8*)(xb + (size_t)tok * DIN + lane * 8) = xo;

    float s[NE];
#pragma unroll
    for (int e = 0; e < NE; ++e) {
      s[e] = v0.x * wg0[e].x + v0.y * wg0[e].y + v0.z * wg0[e].z + v0.w * wg0[e].w +
             v1.x * wg1[e].x + v1.y * wg1[e].y + v1.z * wg1[e].z + v1.w * wg1[e].w;
    }
#pragma unroll
    for (int d = 1; d < 64; d <<= 1) {
#pragma unroll
      for (int e = 0; e < NE; ++e) s[e] += __shfl_xor(s[e], d, 64);
    }
    if (lane == 0) {
      float sc[NE];
#pragma unroll
      for (int e = 0; e < NE; ++e) sc[e] = s[e] + bgr[e];
      int e0 = 0;
#pragma unroll
      for (int e = 1; e < NE; ++e) if (sc[e] > sc[e0]) e0 = e;   // strict >: lowest idx wins ties
      int e1 = (e0 == 0) ? 1 : 0;
#pragma unroll
      for (int e = 0; e < NE; ++e) if (e != e0 && sc[e] > sc[e1]) e1 = e;
      float t = expf(sc[e1] - sc[e0]);                            // <= 1
      float inv = 1.0f / (1.0f + t);                              // w0
      tki[tok] = make_int2(e0, e1);
      tkw[tok] = make_float2(inv, t);
      atomicAdd(&hist[e0 * 8 + e1], 1);
    }
  }
  __syncthreads();
  if (tid < 64) atomicAdd(&meta[M_CNT(tid)], hist[tid]);
}

// ---------------- scan + tile->bucket map ----------------
__global__ void k_scan(int* meta) {
  int tid = threadIdx.x;  // 64 threads
  if (tid == 0) {
    int off = 0;
    for (int g = 0; g < 64; ++g) { meta[M_OFF + g] = off; off += meta[M_CNT(g)]; }
    meta[M_OFF + 64] = off;
    int t = 0;
    for (int g = 0; g < 64; ++g) { meta[M_T0 + g] = t; t += (meta[M_CNT(g)] + TB - 1) / TB; }
    meta[M_T0 + 64] = t;
    meta[M_NW] = t * 4;
  }
  __syncthreads();
  int t0 = meta[M_T0 + tid], t1 = meta[M_T0 + tid + 1];
  for (int t = t0; t < t1; ++t) meta[M_MAP + t] = tid;
}

// ---------------- scatter: one pair-bucket per token, block reservation ----------------
__global__ void __launch_bounds__(256) k_scatter(const int2* __restrict__ tki,
                                                 int* __restrict__ list,
                                                 int* __restrict__ meta) {
  __shared__ int lcnt[64];
  __shared__ int lbase[64];
  int tid = threadIdx.x;
  if (tid < 64) lcnt[tid] = 0;
  __syncthreads();
  int t = blockIdx.x * 256 + tid;
  int2 e = tki[t];
  int bkt = e.x * 8 + e.y;
  int p = atomicAdd(&lcnt[bkt], 1);
  __syncthreads();
  if (tid < 64) lbase[tid] = atomicAdd(&meta[M_CUR(tid)], lcnt[tid]);
  __syncthreads();
  list[meta[M_OFF + bkt] + lbase[bkt] + p] = t;
}

// ---------------- fused pair-bucket gather GEMM ----------------
// 128 tokens x 128 outs per block, BK=64, 4 waves (2x2), 4x4 frags of 16x16x32.
// K=1024: phase0 = expert e1, in-register rescale by t_j, phase1 = expert e0.
// XCD-aware decode: 4 N-blocks of an M-tile share one XCD's L2 (A reuse).
__global__ void __launch_bounds__(256) k_moe_gemm(
    const unsigned short* __restrict__ xb, const unsigned short* __restrict__ wb,
    const float* __restrict__ bias, const float2* __restrict__ tkw,
    const int* __restrict__ list, const int* __restrict__ meta,
    float* __restrict__ out) {
  __shared__ __align__(16) unsigned short As[2][TB * 64];
  __shared__ __align__(16) unsigned short Bs[2][128 * 64];
  __shared__ int tok_s[TB];
  __shared__ float w0_s[TB];
  __shared__ float t_s[TB];

  int NW = meta[M_NW];
  int pb = blockIdx.x;
  int work = (pb & 7) * PER_XCD + (pb >> 3);
  if (work >= NW) return;
  int mt = work >> 2, nb = work & 3;
  int bkt = meta[M_MAP + mt];
  int e0 = bkt >> 3, e1 = bkt & 7;
  int cnt = meta[M_CNT(bkt)];
  int goff = meta[M_OFF + bkt];
  int row0 = (mt - meta[M_T0 + bkt]) * TB;
  int bn0 = nb * 128;

  int tid = threadIdx.x;
  if (tid < TB) {
    int r = row0 + tid;
    int t = (r < cnt) ? list[goff + r] : -1;
    tok_s[tid] = t;
    float2 wt = (t >= 0) ? tkw[t] : make_float2(0.f, 0.f);
    w0_s[tid] = wt.x;
    t_s[tid]  = wt.y;
  }
  __syncthreads();

  int wid = tid >> 6, lane = tid & 63;
  // staging: wave w fills rows [w*32, w*32+32); 8 lanes x 16B = one 128B k-row
  int sseg = lane & 7;
  int srow = wid * 32 + (lane >> 3);
  int tokS[4];
#pragma unroll
  for (int j = 0; j < 4; ++j) {
    int t = tok_s[srow + j * 8];
    tokS[j] = (t < 0) ? tok_s[0] : t;   // tok_s[0] valid for every launched tile
  }
  const unsigned short* aSrc[4];
#pragma unroll
  for (int j = 0; j < 4; ++j) aSrc[j] = xb + (size_t)tokS[j] * DIN + sseg * 8;
  const unsigned short* bSrc0 = wb + (size_t)(e1 * DOUT + bn0 + srow) * DIN + sseg * 8; // phase 0
  const unsigned short* bSrc1 = wb + (size_t)(e0 * DOUT + bn0 + srow) * DIN + sseg * 8; // phase 1

  int wr = wid >> 1, wc = wid & 1;
  int lrow = lane & 15, hi = lane >> 4;

  f32x4 acc[4][4];
#pragma unroll
  for (int m = 0; m < 4; ++m)
#pragma unroll
    for (int n = 0; n < 4; ++n) acc[m][n] = (f32x4){0.f, 0.f, 0.f, 0.f};

  // prologue: stage kt=0 (expert e1, ko=0)
#pragma unroll
  for (int j = 0; j < 4; ++j) {
    gl16(aSrc[j], &As[0][(wid * 32 + j * 8) * 64]);
    gl16(bSrc0 + (size_t)j * 8 * DIN, &Bs[0][(wid * 32 + j * 8) * 64]);
  }
  __syncthreads();

  int cur = 0;
  for (int kt = 0; kt < 16; ++kt) {
    if (kt + 1 < 16) {
      int ko = ((kt + 1) & 7) * 64;
      const unsigned short* bS = (kt + 1 < 8) ? bSrc0 : bSrc1;
#pragma unroll
      for (int j = 0; j < 4; ++j) {
        gl16(aSrc[j] + ko, &As[cur ^ 1][(wid * 32 + j * 8) * 64]);
        gl16(bS + (size_t)j * 8 * DIN + ko, &Bs[cur ^ 1][(wid * 32 + j * 8) * 64]);
      }
    }
    if (kt == 8) {  // acc = out_e1 complete -> scale by t_j before accumulating e0
#pragma unroll
      for (int m = 0; m < 4; ++m) {
        int rb = wr * 64 + m * 16 + hi * 4;
        float t0 = t_s[rb], t1v = t_s[rb + 1], t2 = t_s[rb + 2], t3 = t_s[rb + 3];
#pragma unroll
        for (int n = 0; n < 4; ++n) {
          acc[m][n][0] *= t0; acc[m][n][1] *= t1v;
          acc[m][n][2] *= t2; acc[m][n][3] *= t3;
        }
      }
    }
#pragma unroll
    for (int kk = 0; kk < 2; ++kk) {
      short8 af[4], bf[4];
#pragma unroll
      for (int m = 0; m < 4; ++m)
        af[m] = *(const short8*)&As[cur][(wr * 64 + m * 16 + lrow) * 64 + kk * 32 + hi * 8];
#pragma unroll
      for (int n = 0; n < 4; ++n)
        bf[n] = *(const short8*)&Bs[cur][(wc * 64 + n * 16 + lrow) * 64 + kk * 32 + hi * 8];
#pragma unroll
      for (int m = 0; m < 4; ++m)
#pragma unroll
        for (int n = 0; n < 4; ++n) acc[m][n] = mfma16(af[m], bf[n], acc[m][n]);
    }
    __syncthreads();
    cur ^= 1;
  }

  // epilogue: token = wr*64+m*16+hi*4+j, col = bn0+wc*64+n*16+lrow
  // out = w0*(acc + b_e0 + t*b_e1)   (acc = out_e0 + t*out_e1)
#pragma unroll
  for (int m = 0; m < 4; ++m) {
    int rb = wr * 64 + m * 16 + hi * 4;
    int tj[4]; float wj[4]; float ttj[4];
#pragma unroll
    for (int j = 0; j < 4; ++j) {
      tj[j] = tok_s[rb + j]; wj[j] = w0_s[rb + j]; ttj[j] = t_s[rb + j];
    }
#pragma unroll
    for (int n = 0; n < 4; ++n) {
      int col = bn0 + wc * 64 + n * 16 + lrow;
      float bv0 = bias[e0 * DOUT + col];
      float bv1 = bias[e1 * DOUT + col];
#pragma unroll
      for (int j = 0; j < 4; ++j) {
        if (tj[j] >= 0) {
          out[(size_t)tj[j] * DOUT + col] = wj[j] * (acc[m][n][j] + bv0 + ttj[j] * bv1);
        }
      }
    }
  }
}

extern "C" void kernel_launch(void* const* d_in, const int* in_sizes, int n_in,
                              void* d_out, int out_size, void* d_ws, size_t ws_size,
                              hipStream_t stream) {
  const float* x  = (const float*)d_in[0];
  const float* W  = (const float*)d_in[1];
  const float* b  = (const float*)d_in[2];
  const float* Wg = (const float*)d_in[3];
  const float* bg = (const float*)d_in[4];
  float* out = (float*)d_out;

  char* ws = (char*)d_ws;
  unsigned short* xb  = (unsigned short*)(ws);                    // 64 MB
  unsigned short* wb  = (unsigned short*)(ws + 67108864);         // 4 MB
  int2*   tki  = (int2*)(ws + 71303168);                          // 512 KB
  float2* tkw  = (float2*)(ws + 71827456);                        // 512 KB
  int*    list = (int*)(ws + 72351744);                           // 256 KB
  int*    meta = (int*)(ws + 72876032);                           // M_TOTAL ints

  hipMemsetAsync(meta, 0, M_TOTAL * sizeof(int), stream);
  k_convert_w<<<NE * DOUT * DIN / (256 * 8), 256, 0, stream>>>(W, wb);
  k_gate<<<2048, 256, 0, stream>>>(x, Wg, bg, xb, tki, tkw, meta);
  k_scan<<<1, 64, 0, stream>>>(meta);
  k_scatter<<<N_TOK / 256, 256, 0, stream>>>(tki, list, meta);
  k_moe_gemm<<<GRID_GEMM, 256, 0, stream>>>(xb, wb, b, tkw, list, meta, out);
}

// Round 5
// 365.668 us; speedup vs baseline: 6.7974x; 1.1791x over previous
//
#include <hip/hip_runtime.h>
#include <hip/hip_bf16.h>
#include <stdint.h>

#define N_TOK 65536
#define DIN   512
#define DOUT  512
#define NE    8
#define TB    128            // tokens per GEMM M-tile
#define NMT_MAX 576          // worst-case M-tiles: 512 full + <=56 partial (+pad)
#define GRID_GEMM (NMT_MAX * 4)   // 2304, divisible by 8
#define PER_XCD   (GRID_GEMM / 8) // 288

// meta layout (ints); atomically-updated counters padded to 64B lines:
#define M_CNT(g)  ((g) * 16)        // 64 pair-bucket counters [0,1024)
#define M_OFF     1024              // bucket offsets [1024..1088]
#define M_T0      1090              // M-tile offsets [1090..1154]
#define M_NW      1156              // total work items (tiles*4)
#define M_CUR(g)  (1216 + (g) * 16) // 64 scatter cursors [1216,2240)
#define M_MAP     2240              // tile -> bucket map [2240,2240+NMT_MAX)
#define M_TOTAL   (2240 + NMT_MAX)

typedef __attribute__((ext_vector_type(8))) short          short8;
typedef __attribute__((ext_vector_type(8))) __bf16         bf16x8;
typedef __attribute__((ext_vector_type(8))) unsigned short ushort8;
typedef __attribute__((ext_vector_type(4))) float          f32x4;

// round-to-nearest-even fp32 -> bf16
__device__ __forceinline__ unsigned short f2bf(float f) {
  union { float f; unsigned u; } c; c.f = f;
  unsigned r = c.u + 0x7FFFu + ((c.u >> 16) & 1u);
  return (unsigned short)(r >> 16);
}

__device__ __forceinline__ f32x4 mfma16(short8 a, short8 b, f32x4 c) {
  return __builtin_amdgcn_mfma_f32_16x16x32_bf16(
      __builtin_bit_cast(bf16x8, a), __builtin_bit_cast(bf16x8, b), c, 0, 0, 0);
}

// async global->LDS, 16B/lane; LDS dest = wave-uniform base + lane*16 (linear),
// global src is per-lane (gather + swizzle applied on the SOURCE address).
__device__ __forceinline__ void gl16(const void* g, void* l) {
  __builtin_amdgcn_global_load_lds(
      (const __attribute__((address_space(1))) unsigned int*)g,
      (__attribute__((address_space(3))) unsigned int*)l, 16, 0, 0);
}

// ---------------- W fp32 -> bf16 ----------------
__global__ void __launch_bounds__(256) k_convert_w(const float* __restrict__ W,
                                                   unsigned short* __restrict__ wb) {
  int i = (blockIdx.x * 256 + threadIdx.x) * 8;
  float4 a = *(const float4*)(W + i);
  float4 b = *(const float4*)(W + i + 4);
  ushort8 o;
  o[0] = f2bf(a.x); o[1] = f2bf(a.y); o[2] = f2bf(a.z); o[3] = f2bf(a.w);
  o[4] = f2bf(b.x); o[5] = f2bf(b.y); o[6] = f2bf(b.z); o[7] = f2bf(b.w);
  *(ushort8*)(wb + i) = o;
}

// ---------------- gate: fp32 scores, top-2, softmax; fused x->bf16 ----------------
// tkw = (w0, t) with w0 = 1/(1+t), t = exp(sc1 - sc0) <= 1 (so w1 = w0*t).
__global__ void __launch_bounds__(256, 4) k_gate(const float* __restrict__ x,
                                                 const float* __restrict__ Wg,
                                                 const float* __restrict__ bg,
                                                 unsigned short* __restrict__ xb,
                                                 int2* __restrict__ tki,
                                                 float2* __restrict__ tkw,
                                                 int* __restrict__ meta) {
  __shared__ int hist[64];
  int tid = threadIdx.x;
  if (tid < 64) hist[tid] = 0;
  int wid = tid >> 6, lane = tid & 63;

  float4 wg0[NE], wg1[NE];
#pragma unroll
  for (int e = 0; e < NE; ++e) {
    wg0[e] = *(const float4*)(Wg + e * DIN + lane * 8);
    wg1[e] = *(const float4*)(Wg + e * DIN + lane * 8 + 4);
  }
  float bgr[NE];
#pragma unroll
  for (int e = 0; e < NE; ++e) bgr[e] = bg[e];
  __syncthreads();

  for (int tok = blockIdx.x * 4 + wid; tok < N_TOK; tok += gridDim.x * 4) {
    const float* xr = x + (size_t)tok * DIN + lane * 8;
    float4 v0 = *(const float4*)(xr);
    float4 v1 = *(const float4*)(xr + 4);

    ushort8 xo;
    xo[0] = f2bf(v0.x); xo[1] = f2bf(v0.y); xo[2] = f2bf(v0.z); xo[3] = f2bf(v0.w);
    xo[4] = f2bf(v1.x); xo[5] = f2bf(v1.y); xo[6] = f2bf(v1.z); xo[7] = f2bf(v1.w);
    *(ushort8*)(xb + (size_t)tok * DIN + lane * 8) = xo;

    float s[NE];
#pragma unroll
    for (int e = 0; e < NE; ++e) {
      s[e] = v0.x * wg0[e].x + v0.y * wg0[e].y + v0.z * wg0[e].z + v0.w * wg0[e].w +
             v1.x * wg1[e].x + v1.y * wg1[e].y + v1.z * wg1[e].z + v1.w * wg1[e].w;
    }
#pragma unroll
    for (int d = 1; d < 64; d <<= 1) {
#pragma unroll
      for (int e = 0; e < NE; ++e) s[e] += __shfl_xor(s[e], d, 64);
    }
    if (lane == 0) {
      float sc[NE];
#pragma unroll
      for (int e = 0; e < NE; ++e) sc[e] = s[e] + bgr[e];
      int e0 = 0;
#pragma unroll
      for (int e = 1; e < NE; ++e) if (sc[e] > sc[e0]) e0 = e;   // strict >: lowest idx wins ties
      int e1 = (e0 == 0) ? 1 : 0;
#pragma unroll
      for (int e = 0; e < NE; ++e) if (e != e0 && sc[e] > sc[e1]) e1 = e;
      float t = expf(sc[e1] - sc[e0]);                            // <= 1
      float inv = 1.0f / (1.0f + t);                              // w0
      tki[tok] = make_int2(e0, e1);
      tkw[tok] = make_float2(inv, t);
      atomicAdd(&hist[e0 * 8 + e1], 1);
    }
  }
  __syncthreads();
  if (tid < 64) atomicAdd(&meta[M_CNT(tid)], hist[tid]);
}

// ---------------- scan: one wave, shfl prefix sums + tile->bucket map ----------------
__global__ void k_scan(int* meta) {
  int lane = threadIdx.x & 63;  // launched with 64 threads = 1 wave
  int cnt = meta[M_CNT(lane)];
  int nt  = (cnt + TB - 1) / TB;
  int po = cnt, pt = nt;
#pragma unroll
  for (int d = 1; d < 64; d <<= 1) {
    int vo = __shfl_up(po, d, 64);
    int vt = __shfl_up(pt, d, 64);
    if (lane >= d) { po += vo; pt += vt; }
  }
  meta[M_OFF + lane] = po - cnt;   // exclusive
  int t0 = pt - nt;
  meta[M_T0 + lane] = t0;
  if (lane == 63) {
    meta[M_OFF + 64] = po;
    meta[M_T0 + 64]  = pt;
    meta[M_NW] = pt * 4;
  }
  for (int t = t0; t < pt; ++t) meta[M_MAP + t] = lane;
}

// ---------------- scatter: one pair-bucket per token, block reservation ----------------
__global__ void __launch_bounds__(256) k_scatter(const int2* __restrict__ tki,
                                                 int* __restrict__ list,
                                                 int* __restrict__ meta) {
  __shared__ int lcnt[64];
  __shared__ int lbase[64];
  int tid = threadIdx.x;
  if (tid < 64) lcnt[tid] = 0;
  __syncthreads();
  int t = blockIdx.x * 256 + tid;
  int2 e = tki[t];
  int bkt = e.x * 8 + e.y;
  int p = atomicAdd(&lcnt[bkt], 1);
  __syncthreads();
  if (tid < 64) lbase[tid] = atomicAdd(&meta[M_CUR(tid)], lcnt[tid]);
  __syncthreads();
  list[meta[M_OFF + bkt] + lbase[bkt] + p] = t;
}

// ---------------- fused pair-bucket gather GEMM (m97 2-barrier, swizzled LDS) ----
// 128 tokens x 128 outs per block, BK=64, 4 waves (2x2), 4x4 frags of 16x16x32.
// K=1024: phase0 = expert e1, in-register rescale by t_j, phase1 = expert e0.
// Single-buffered LDS (33.5KB -> 4 blocks/CU); XOR swizzle: source segment
// pre-swizzled (sseg ^ (srow&7)), ds_read slot applies the same involution.
__global__ void __launch_bounds__(256) k_moe_gemm(
    const unsigned short* __restrict__ xb, const unsigned short* __restrict__ wb,
    const float* __restrict__ bias, const float2* __restrict__ tkw,
    const int* __restrict__ list, const int* __restrict__ meta,
    float* __restrict__ out) {
  __shared__ __align__(16) unsigned short As[TB * 64];
  __shared__ __align__(16) unsigned short Bs[128 * 64];
  __shared__ int tok_s[TB];
  __shared__ float w0_s[TB];
  __shared__ float t_s[TB];

  int NW = meta[M_NW];
  int pb = blockIdx.x;
  int work = (pb & 7) * PER_XCD + (pb >> 3);
  if (work >= NW) return;
  int mt = work >> 2, nb = work & 3;
  int bkt = meta[M_MAP + mt];
  int e0 = bkt >> 3, e1 = bkt & 7;
  int cnt = meta[M_CNT(bkt)];
  int goff = meta[M_OFF + bkt];
  int row0 = (mt - meta[M_T0 + bkt]) * TB;
  int bn0 = nb * 128;

  int tid = threadIdx.x;
  if (tid < TB) {
    int r = row0 + tid;
    int t = (r < cnt) ? list[goff + r] : -1;
    tok_s[tid] = t;
    float2 wt = (t >= 0) ? tkw[t] : make_float2(0.f, 0.f);
    w0_s[tid] = wt.x;
    t_s[tid]  = wt.y;
  }
  __syncthreads();

  int wid = tid >> 6, lane = tid & 63;
  // staging: wave w fills rows [w*32, w*32+32); LDS dest linear (lane*16B),
  // global source segment swizzled: sw = sseg ^ (srow&7). (j*8 preserves srow&7.)
  int sseg = lane & 7;
  int srow = wid * 32 + (lane >> 3);
  int sw = sseg ^ (srow & 7);
  int tokS[4];
#pragma unroll
  for (int j = 0; j < 4; ++j) {
    int t = tok_s[srow + j * 8];
    tokS[j] = (t < 0) ? tok_s[0] : t;   // tok_s[0] valid for every launched tile
  }
  const unsigned short* aSrc[4];
#pragma unroll
  for (int j = 0; j < 4; ++j) aSrc[j] = xb + (size_t)tokS[j] * DIN + sw * 8;
  const unsigned short* bSrc0 = wb + (size_t)(e1 * DOUT + bn0 + srow) * DIN + sw * 8; // phase 0
  const unsigned short* bSrc1 = wb + (size_t)(e0 * DOUT + bn0 + srow) * DIN + sw * 8; // phase 1

  int wr = wid >> 1, wc = wid & 1;
  int lrow = lane & 15, hi = lane >> 4;
  int l7 = lrow & 7;

  f32x4 acc[4][4];
#pragma unroll
  for (int m = 0; m < 4; ++m)
#pragma unroll
    for (int n = 0; n < 4; ++n) acc[m][n] = (f32x4){0.f, 0.f, 0.f, 0.f};

  for (int kt = 0; kt < 16; ++kt) {
    if (kt > 0) __syncthreads();        // all waves done reading previous tile
    {
      int ko = (kt & 7) * 64;
      const unsigned short* bS = (kt < 8) ? bSrc0 : bSrc1;
#pragma unroll
      for (int j = 0; j < 4; ++j) {
        gl16(aSrc[j] + ko, &As[(wid * 32 + j * 8) * 64]);
        gl16(bS + (size_t)j * 8 * DIN + ko, &Bs[(wid * 32 + j * 8) * 64]);
      }
    }
    if (kt == 8) {  // acc = out_e1 complete -> scale by t_j before accumulating e0
#pragma unroll
      for (int m = 0; m < 4; ++m) {
        int rb = wr * 64 + m * 16 + hi * 4;
        float t0 = t_s[rb], t1v = t_s[rb + 1], t2 = t_s[rb + 2], t3 = t_s[rb + 3];
#pragma unroll
        for (int n = 0; n < 4; ++n) {
          acc[m][n][0] *= t0; acc[m][n][1] *= t1v;
          acc[m][n][2] *= t2; acc[m][n][3] *= t3;
        }
      }
    }
    __syncthreads();                    // staging complete (vmcnt drained)
#pragma unroll
    for (int kk = 0; kk < 2; ++kk) {
      int slot = (kk * 4 + hi) ^ l7;    // read-side involution
      short8 af[4], bf[4];
#pragma unroll
      for (int m = 0; m < 4; ++m)
        af[m] = *(const short8*)&As[(wr * 64 + m * 16 + lrow) * 64 + slot * 8];
#pragma unroll
      for (int n = 0; n < 4; ++n)
        bf[n] = *(const short8*)&Bs[(wc * 64 + n * 16 + lrow) * 64 + slot * 8];
#pragma unroll
      for (int m = 0; m < 4; ++m)
#pragma unroll
        for (int n = 0; n < 4; ++n) acc[m][n] = mfma16(af[m], bf[n], acc[m][n]);
    }
  }

  // epilogue: token = wr*64+m*16+hi*4+j, col = bn0+wc*64+n*16+lrow
  // out = w0*(acc + b_e0 + t*b_e1)   (acc = out_e0 + t*out_e1)
#pragma unroll
  for (int m = 0; m < 4; ++m) {
    int rb = wr * 64 + m * 16 + hi * 4;
    int tj[4]; float wj[4]; float ttj[4];
#pragma unroll
    for (int j = 0; j < 4; ++j) {
      tj[j] = tok_s[rb + j]; wj[j] = w0_s[rb + j]; ttj[j] = t_s[rb + j];
    }
#pragma unroll
    for (int n = 0; n < 4; ++n) {
      int col = bn0 + wc * 64 + n * 16 + lrow;
      float bv0 = bias[e0 * DOUT + col];
      float bv1 = bias[e1 * DOUT + col];
#pragma unroll
      for (int j = 0; j < 4; ++j) {
        if (tj[j] >= 0) {
          out[(size_t)tj[j] * DOUT + col] = wj[j] * (acc[m][n][j] + bv0 + ttj[j] * bv1);
        }
      }
    }
  }
}

extern "C" void kernel_launch(void* const* d_in, const int* in_sizes, int n_in,
                              void* d_out, int out_size, void* d_ws, size_t ws_size,
                              hipStream_t stream) {
  const float* x  = (const float*)d_in[0];
  const float* W  = (const float*)d_in[1];
  const float* b  = (const float*)d_in[2];
  const float* Wg = (const float*)d_in[3];
  const float* bg = (const float*)d_in[4];
  float* out = (float*)d_out;

  char* ws = (char*)d_ws;
  unsigned short* xb  = (unsigned short*)(ws);                    // 64 MB
  unsigned short* wb  = (unsigned short*)(ws + 67108864);         // 4 MB
  int2*   tki  = (int2*)(ws + 71303168);                          // 512 KB
  float2* tkw  = (float2*)(ws + 71827456);                        // 512 KB
  int*    list = (int*)(ws + 72351744);                           // 256 KB
  int*    meta = (int*)(ws + 72876032);                           // M_TOTAL ints

  hipMemsetAsync(meta, 0, M_TOTAL * sizeof(int), stream);
  k_convert_w<<<NE * DOUT * DIN / (256 * 8), 256, 0, stream>>>(W, wb);
  k_gate<<<2048, 256, 0, stream>>>(x, Wg, bg, xb, tki, tkw, meta);
  k_scan<<<1, 64, 0, stream>>>(meta);
  k_scatter<<<N_TOK / 256, 256, 0, stream>>>(tki, list, meta);
  k_moe_gemm<<<GRID_GEMM, 256, 0, stream>>>(xb, wb, b, tkw, list, meta, out);
}